// Round 1
// baseline (197.089 us; speedup 1.0000x reference)
//
#include <hip/hip_runtime.h>

typedef unsigned short u16;
typedef unsigned int u32;
typedef __attribute__((ext_vector_type(8))) __bf16 bf16x8;
typedef __attribute__((ext_vector_type(4))) float f32x4;
typedef __attribute__((ext_vector_type(8))) unsigned short u16x8;
typedef __attribute__((ext_vector_type(4))) unsigned short u16x4;

__device__ __forceinline__ u16 f2bf(float f) {
    u32 u = __builtin_bit_cast(u32, f);
    u += 0x7fffu + ((u >> 16) & 1u);   // round-to-nearest-even
    return (u16)(u >> 16);
}

// ---------------- conversions ----------------
__global__ __launch_bounds__(256) void conv_h_kernel(const float* __restrict__ h,
                                                     u16* __restrict__ hb) {
    int i = blockIdx.x * 256 + threadIdx.x;
    float4 v = ((const float4*)h)[i];
    u16x4 o = { f2bf(v.x), f2bf(v.y), f2bf(v.z), f2bf(v.w) };
    ((u16x4*)hb)[i] = o;
}

// W [R][C] f32  ->  Wt [C][R] bf16   (transpose + convert)
__global__ __launch_bounds__(256) void conv_wt_kernel(const float* __restrict__ W,
                                                      u16* __restrict__ Wt,
                                                      int R, int C) {
    __shared__ float tile[32][33];
    int t = threadIdx.x;
    int r = t >> 3, c4 = (t & 7) * 4;
    int gx = blockIdx.x * 32, gy = blockIdx.y * 32;  // gx: col base, gy: row base
    float4 v = *(const float4*)&W[(size_t)(gy + r) * C + gx + c4];
    tile[r][c4 + 0] = v.x; tile[r][c4 + 1] = v.y;
    tile[r][c4 + 2] = v.z; tile[r][c4 + 3] = v.w;
    __syncthreads();
    // Wt[(gx+r)][gy+c4+j] = W[gy+c4+j][gx+r]
    u16x4 o = { f2bf(tile[c4 + 0][r]), f2bf(tile[c4 + 1][r]),
                f2bf(tile[c4 + 2][r]), f2bf(tile[c4 + 3][r]) };
    *(u16x4*)&Wt[(size_t)(gx + r) * R + gy + c4] = o;
}

// ---------------- GEMM: C[M][N] = A[M][K] (bf16) x Bt[N][K]^T (bf16) ----------------
// MODE 0: store bf16 C.  MODE 1: X = acc + H (f32 residual), f32 out.
template <int MODE>
__global__ __launch_bounds__(256) void gemm_bt_kernel(
        const u16* __restrict__ A, const u16* __restrict__ Bt,
        u16* __restrict__ Cb, const float* __restrict__ H, float* __restrict__ X,
        int M, int N, int K) {
    constexpr int LDT = 40;                 // 32 + 8 pad (elems) -> 2-way-free banks
    __shared__ u16 alds[2][128 * LDT];
    __shared__ u16 blds[2][128 * LDT];
    const int t = threadIdx.x;
    const int lane = t & 63;
    const int wave = t >> 6;
    const int wm = wave >> 1, wn = wave & 1;
    const int m0 = blockIdx.x * 128;
    const int n0 = blockIdx.y * 128;
    const int nk = K >> 5;

    // staging: thread covers chunks {2t, 2t+1}: row = t>>1, chunk base = 2(t&1)
    const int srow = t >> 1;
    const int sch = (t & 1) * 2;
    const u16* ga = A + (size_t)(m0 + srow) * K + sch * 8;
    const u16* gb = Bt + (size_t)(n0 + srow) * K + sch * 8;
    const int wo = srow * LDT + sch * 8;

    u16x8 ra0 = *(const u16x8*)(ga);
    u16x8 ra1 = *(const u16x8*)(ga + 8);
    u16x8 rb0 = *(const u16x8*)(gb);
    u16x8 rb1 = *(const u16x8*)(gb + 8);
    *(u16x8*)&alds[0][wo] = ra0;  *(u16x8*)&alds[0][wo + 8] = ra1;
    *(u16x8*)&blds[0][wo] = rb0;  *(u16x8*)&blds[0][wo + 8] = rb1;

    f32x4 acc[4][4] = {};
    const int ko = (lane >> 4) * 8;
    const int arow_base = wm * 64 + (lane & 15);
    const int brow_base = wn * 64 + (lane & 15);

    int cur = 0;
    for (int kt = 0; kt < nk; ++kt) {
        __syncthreads();                    // buf[cur] writes visible to all waves
        if (kt + 1 < nk) {                  // prefetch next tile into regs
            const u16* gan = ga + (kt + 1) * 32;
            const u16* gbn = gb + (kt + 1) * 32;
            ra0 = *(const u16x8*)(gan);
            ra1 = *(const u16x8*)(gan + 8);
            rb0 = *(const u16x8*)(gbn);
            rb1 = *(const u16x8*)(gbn + 8);
        }
        bf16x8 afrag[4], bfrag[4];
#pragma unroll
        for (int m = 0; m < 4; ++m)
            afrag[m] = *(const bf16x8*)&alds[cur][(arow_base + m * 16) * LDT + ko];
#pragma unroll
        for (int n = 0; n < 4; ++n)
            bfrag[n] = *(const bf16x8*)&blds[cur][(brow_base + n * 16) * LDT + ko];
#pragma unroll
        for (int m = 0; m < 4; ++m)
#pragma unroll
            for (int n = 0; n < 4; ++n)
                acc[m][n] = __builtin_amdgcn_mfma_f32_16x16x32_bf16(afrag[m], bfrag[n],
                                                                   acc[m][n], 0, 0, 0);
        if (kt + 1 < nk) {                  // write-late into the other buffer
            *(u16x8*)&alds[cur ^ 1][wo] = ra0;  *(u16x8*)&alds[cur ^ 1][wo + 8] = ra1;
            *(u16x8*)&blds[cur ^ 1][wo] = rb0;  *(u16x8*)&blds[cur ^ 1][wo + 8] = rb1;
        }
        cur ^= 1;
    }

#pragma unroll
    for (int m = 0; m < 4; ++m)
#pragma unroll
        for (int n = 0; n < 4; ++n)
#pragma unroll
            for (int r = 0; r < 4; ++r) {
                int row = m0 + wm * 64 + m * 16 + (lane >> 4) * 4 + r;
                int col = n0 + wn * 64 + n * 16 + (lane & 15);
                size_t idx = (size_t)row * N + col;
                if (MODE == 0) Cb[idx] = f2bf(acc[m][n][r]);
                else           X[idx] = acc[m][n][r] + H[idx];
            }
}

// ---------------- V transpose: qkvb v-part -> vt[(pair*64+dh)][s] ----------------
__global__ __launch_bounds__(256) void transpose_v_kernel(const u16* __restrict__ qkvb,
                                                          u16* __restrict__ vt) {
    __shared__ u16 tl[64][72];
    const int t = threadIdx.x;
    const int p = blockIdx.y;             // pair: n = p>>1, b = p&1
    const int nn = p >> 1, b = p & 1;
    const int s0 = blockIdx.x * 64;
    const int r = t >> 2;                 // s row 0..63
    const int ch = (t & 3) * 2;           // chunks {ch, ch+1} of 8 elems
    const u16* g = qkvb + ((size_t)(s0 + r) * 2 + b) * 3072 + 2048 + nn * 64;
    *(u16x8*)&tl[r][ch * 8]     = *(const u16x8*)(g + ch * 8);
    *(u16x8*)&tl[r][ch * 8 + 8] = *(const u16x8*)(g + ch * 8 + 8);
    __syncthreads();
    const int dh = t >> 2;                // 0..63
    const int sc = (t & 3) * 2;
    u16* o = vt + ((size_t)p * 64 + dh) * 2048 + s0;
#pragma unroll
    for (int q = 0; q < 2; ++q) {
        int scq = sc + q;
        u16x8 v;
#pragma unroll
        for (int j = 0; j < 8; ++j) v[j] = tl[scq * 8 + j][dh];
        *(u16x8*)(o + scq * 8) = v;
    }
}

// ---------------- causal flash attention ----------------
// block: one (pair, 64-row Q tile); 4 waves x 16 rows; KV tiles of 64.
__global__ __launch_bounds__(256) void attn_kernel(const u16* __restrict__ qkvb,
                                                   const u16* __restrict__ vt,
                                                   u16* __restrict__ attnb) {
    constexpr int LKT = 72;               // 64 + 8 pad
    __shared__ u16 klds[64 * LKT];
    __shared__ u16 vlds[64 * LKT];
    __shared__ u16 plds[4][16 * LKT];
    const int t = threadIdx.x;
    const int lane = t & 63;
    const int w = t >> 6;
    const int p = blockIdx.y;
    const int nn = p >> 1, b = p & 1;
    const int qt = (int)gridDim.x - 1 - (int)blockIdx.x;  // heavy blocks first
    const int i0 = qt * 64;
    const float scale = 0.125f;           // 1/sqrt(64)

    // Q fragments stay in registers (rows i0 + w*16 + (lane&15))
    const int qrow = i0 + w * 16 + (lane & 15);
    const u16* qg = qkvb + ((size_t)qrow * 2 + b) * 3072 + nn * 64 + (lane >> 4) * 8;
    bf16x8 qa0 = *(const bf16x8*)(qg);
    bf16x8 qa1 = *(const bf16x8*)(qg + 32);

    f32x4 o[4] = {};
    float mrun[4] = { -1e30f, -1e30f, -1e30f, -1e30f };
    float lrun[4] = { 0.f, 0.f, 0.f, 0.f };

    const int srow = t >> 2;
    const int sch = (t & 3) * 2;
    const u16* kg = qkvb + 1024 + nn * 64 + sch * 8;
    const u16* vg = vt + ((size_t)p * 64 + srow) * 2048 + sch * 8;

    const int nt = i0 / 64 + 1;
    for (int jt = 0; jt < nt; ++jt) {
        const int j0 = jt * 64;
        __syncthreads();                  // prior tile's reads complete
        {
            const u16* kgp = kg + ((size_t)(j0 + srow) * 2 + b) * 3072;
            u16x8 k0 = *(const u16x8*)(kgp);
            u16x8 k1 = *(const u16x8*)(kgp + 8);
            const u16* vgp = vg + j0;
            u16x8 v0 = *(const u16x8*)(vgp);
            u16x8 v1 = *(const u16x8*)(vgp + 8);
            *(u16x8*)&klds[srow * LKT + sch * 8] = k0;
            *(u16x8*)&klds[srow * LKT + sch * 8 + 8] = k1;
            *(u16x8*)&vlds[srow * LKT + sch * 8] = v0;
            *(u16x8*)&vlds[srow * LKT + sch * 8 + 8] = v1;
        }
        __syncthreads();

        // QK^T : S[16 rows][64 cols] per wave
        f32x4 s[4] = {};
#pragma unroll
        for (int cf = 0; cf < 4; ++cf) {
            bf16x8 kb0 = *(const bf16x8*)&klds[(cf * 16 + (lane & 15)) * LKT + (lane >> 4) * 8];
            bf16x8 kb1 = *(const bf16x8*)&klds[(cf * 16 + (lane & 15)) * LKT + 32 + (lane >> 4) * 8];
            s[cf] = __builtin_amdgcn_mfma_f32_16x16x32_bf16(qa0, kb0, s[cf], 0, 0, 0);
            s[cf] = __builtin_amdgcn_mfma_f32_16x16x32_bf16(qa1, kb1, s[cf], 0, 0, 0);
        }

        // scale + causal mask + online softmax (row = (lane>>4)*4 + r)
        const int ibase = i0 + w * 16 + (lane >> 4) * 4;
        float pm[4][4];
        float mloc[4] = { -1e30f, -1e30f, -1e30f, -1e30f };
#pragma unroll
        for (int cf = 0; cf < 4; ++cf) {
            int j = j0 + cf * 16 + (lane & 15);
#pragma unroll
            for (int r = 0; r < 4; ++r) {
                float sv = s[cf][r] * scale;
                sv = (j > ibase + r) ? -1e30f : sv;
                pm[cf][r] = sv;
                mloc[r] = fmaxf(mloc[r], sv);
            }
        }
#pragma unroll
        for (int off = 1; off < 16; off <<= 1)
#pragma unroll
            for (int r = 0; r < 4; ++r)
                mloc[r] = fmaxf(mloc[r], __shfl_xor(mloc[r], off, 64));
        float alpha[4], rsum[4];
#pragma unroll
        for (int r = 0; r < 4; ++r) {
            float mnew = fmaxf(mrun[r], mloc[r]);
            alpha[r] = __expf(mrun[r] - mnew);
            mrun[r] = mnew;
            rsum[r] = 0.f;
        }
#pragma unroll
        for (int cf = 0; cf < 4; ++cf)
#pragma unroll
            for (int r = 0; r < 4; ++r) {
                float pv = __expf(pm[cf][r] - mrun[r]);
                pm[cf][r] = pv;
                rsum[r] += pv;
            }
#pragma unroll
        for (int off = 1; off < 16; off <<= 1)
#pragma unroll
            for (int r = 0; r < 4; ++r)
                rsum[r] += __shfl_xor(rsum[r], off, 64);
#pragma unroll
        for (int r = 0; r < 4; ++r) {
            lrun[r] = lrun[r] * alpha[r] + rsum[r];
#pragma unroll
            for (int cf = 0; cf < 4; ++cf) o[cf][r] *= alpha[r];
        }
        // P (D-layout) -> plds, re-read in A-layout for PV
#pragma unroll
        for (int cf = 0; cf < 4; ++cf)
#pragma unroll
            for (int r = 0; r < 4; ++r)
                plds[w][((lane >> 4) * 4 + r) * LKT + cf * 16 + (lane & 15)] = f2bf(pm[cf][r]);
        asm volatile("s_waitcnt lgkmcnt(0)" ::: "memory");
        __builtin_amdgcn_sched_barrier(0);

        // PV: O += P[16][64] x V[64][64]
#pragma unroll
        for (int ks = 0; ks < 2; ++ks) {
            bf16x8 pa = *(const bf16x8*)&plds[w][(lane & 15) * LKT + ks * 32 + (lane >> 4) * 8];
#pragma unroll
            for (int cf = 0; cf < 4; ++cf) {
                bf16x8 vb = *(const bf16x8*)&vlds[(cf * 16 + (lane & 15)) * LKT + ks * 32 + (lane >> 4) * 8];
                o[cf] = __builtin_amdgcn_mfma_f32_16x16x32_bf16(pa, vb, o[cf], 0, 0, 0);
            }
        }
    }

#pragma unroll
    for (int r = 0; r < 4; ++r) {
        float inv = 1.f / lrun[r];
        int srowg = i0 + w * 16 + (lane >> 4) * 4 + r;
        u16* og = attnb + ((size_t)srowg * 2 + b) * 1024 + nn * 64;
#pragma unroll
        for (int cf = 0; cf < 4; ++cf)
            og[cf * 16 + (lane & 15)] = f2bf(o[cf][r] * inv);
    }
}

// ---------------- residual LayerNorm ----------------
__global__ __launch_bounds__(256) void ln_kernel(const float* __restrict__ X,
                                                 const float* __restrict__ gamma,
                                                 const float* __restrict__ beta,
                                                 float* __restrict__ out) {
    __shared__ float red[8];
    const int t = threadIdx.x;
    const int row = blockIdx.x;
    float4 v = ((const float4*)(X + (size_t)row * 1024))[t];
    float s = v.x + v.y + v.z + v.w;
#pragma unroll
    for (int off = 1; off < 64; off <<= 1) s += __shfl_xor(s, off, 64);
    if ((t & 63) == 0) red[t >> 6] = s;
    __syncthreads();
    float mu = (red[0] + red[1] + red[2] + red[3]) * (1.f / 1024.f);
    float dx = v.x - mu, dy = v.y - mu, dz = v.z - mu, dw = v.w - mu;
    float q = dx * dx + dy * dy + dz * dz + dw * dw;
#pragma unroll
    for (int off = 1; off < 64; off <<= 1) q += __shfl_xor(q, off, 64);
    if ((t & 63) == 0) red[4 + (t >> 6)] = q;
    __syncthreads();
    float var = (red[4] + red[5] + red[6] + red[7]) * (1.f / 1024.f);
    float rs = rsqrtf(var + 1e-5f);
    float4 g = ((const float4*)gamma)[t];
    float4 bt = ((const float4*)beta)[t];
    float4 o;
    o.x = dx * rs * g.x + bt.x;
    o.y = dy * rs * g.y + bt.y;
    o.z = dz * rs * g.z + bt.z;
    o.w = dw * rs * g.w + bt.w;
    ((float4*)(out + (size_t)row * 1024))[t] = o;
}

// ---------------- launch ----------------
extern "C" void kernel_launch(void* const* d_in, const int* in_sizes, int n_in,
                              void* d_out, int out_size, void* d_ws, size_t ws_size,
                              hipStream_t stream) {
    const float* h     = (const float*)d_in[0];
    // d_in[1] = attn_mask (deterministic causal triu; applied analytically)
    const float* Wqkv  = (const float*)d_in[2];
    const float* Wo    = (const float*)d_in[3];
    const float* gamma = (const float*)d_in[4];
    const float* beta  = (const float*)d_in[5];
    float* out = (float*)d_out;

    char* ws = (char*)d_ws;
    u16*   hb    = (u16*)(ws);                   //  8,388,608  h bf16 [4096][1024]
    u16*   wqkvt = (u16*)(ws + 8388608);         //  6,291,456  W_qkv^T bf16 [3072][1024]
    u16*   wot   = (u16*)(ws + 14680064);        //  2,097,152  W_o^T bf16 [1024][1024]
    u16*   qkvb  = (u16*)(ws + 16777216);        // 25,165,824  qkv bf16 [4096][3072]
    u16*   vt    = (u16*)(ws + 41943040);        //  8,388,608  V^T bf16 [32*64][2048]
    u16*   attnb = (u16*)(ws + 50331648);        //  8,388,608  attn_vec bf16 [4096][1024]
    float* xbuf  = (float*)(ws + 58720256);      // 16,777,216  h+attn_out f32 — end 75,497,472

    conv_h_kernel<<<4096, 256, 0, stream>>>(h, hb);
    conv_wt_kernel<<<dim3(96, 32), 256, 0, stream>>>(Wqkv, wqkvt, 1024, 3072);
    conv_wt_kernel<<<dim3(32, 32), 256, 0, stream>>>(Wo, wot, 1024, 1024);
    gemm_bt_kernel<0><<<dim3(32, 24), 256, 0, stream>>>(hb, wqkvt, qkvb, nullptr, nullptr,
                                                        4096, 3072, 1024);
    transpose_v_kernel<<<dim3(32, 32), 256, 0, stream>>>(qkvb, vt);
    attn_kernel<<<dim3(32, 32), 256, 0, stream>>>(qkvb, vt, attnb);
    gemm_bt_kernel<1><<<dim3(32, 8), 256, 0, stream>>>(attnb, wot, nullptr, h, xbuf,
                                                       4096, 1024, 1024);
    ln_kernel<<<4096, 256, 0, stream>>>(xbuf, gamma, beta, out);
}

// Round 2
// 122.740 us; speedup vs baseline: 1.6057x; 1.6057x over previous
//
#include <hip/hip_runtime.h>

typedef unsigned short u16;
typedef unsigned int u32;
typedef __attribute__((ext_vector_type(8))) __bf16 bf16x8;
typedef __attribute__((ext_vector_type(4))) float f32x4;
typedef __attribute__((ext_vector_type(8))) unsigned short u16x8;
typedef __attribute__((ext_vector_type(4))) unsigned short u16x4;

__device__ __forceinline__ u16 f2bf(float f) {
    u32 u = __builtin_bit_cast(u32, f);
    u += 0x7fffu + ((u >> 16) & 1u);   // round-to-nearest-even
    return (u16)(u >> 16);
}

__device__ __forceinline__ float fexp2(float x) {
#if __has_builtin(__builtin_amdgcn_exp2f)
    return __builtin_amdgcn_exp2f(x);
#else
    return exp2f(x);
#endif
}

__device__ __forceinline__ float frcp(float x) {
#if __has_builtin(__builtin_amdgcn_rcpf)
    return __builtin_amdgcn_rcpf(x);
#else
    return 1.0f / x;
#endif
}

// ---------------- conversions ----------------
__global__ __launch_bounds__(256) void conv_h_kernel(const float* __restrict__ h,
                                                     u16* __restrict__ hb) {
    int i = blockIdx.x * 256 + threadIdx.x;
    float4 v = ((const float4*)h)[i];
    u16x4 o = { f2bf(v.x), f2bf(v.y), f2bf(v.z), f2bf(v.w) };
    ((u16x4*)hb)[i] = o;
}

// W [R][C] f32 -> Wt [C][R] bf16 (transpose + convert); rows < scale_rows get *scale
__global__ __launch_bounds__(256) void conv_wt_kernel(const float* __restrict__ W,
                                                      u16* __restrict__ Wt,
                                                      int R, int C,
                                                      int scale_rows, float scale) {
    __shared__ float tile[32][33];
    int t = threadIdx.x;
    int r = t >> 3, c4 = (t & 7) * 4;
    int gx = blockIdx.x * 32, gy = blockIdx.y * 32;  // gx: col base, gy: row base
    float4 v = *(const float4*)&W[(size_t)(gy + r) * C + gx + c4];
    tile[r][c4 + 0] = v.x; tile[r][c4 + 1] = v.y;
    tile[r][c4 + 2] = v.z; tile[r][c4 + 3] = v.w;
    __syncthreads();
    float sc = (gx + r < scale_rows) ? scale : 1.0f;
    u16x4 o = { f2bf(tile[c4 + 0][r] * sc), f2bf(tile[c4 + 1][r] * sc),
                f2bf(tile[c4 + 2][r] * sc), f2bf(tile[c4 + 3][r] * sc) };
    *(u16x4*)&Wt[(size_t)(gx + r) * R + gy + c4] = o;
}

// ---------------- GEMM: C[M][N] = A[M][K] (bf16) x Bt[N][K]^T (bf16) ----------------
template <int MODE>
__global__ __launch_bounds__(256) void gemm_bt_kernel(
        const u16* __restrict__ A, const u16* __restrict__ Bt,
        u16* __restrict__ Cb, const float* __restrict__ H, float* __restrict__ X,
        int M, int N, int K) {
    constexpr int LDT = 40;
    __shared__ u16 alds[2][128 * LDT];
    __shared__ u16 blds[2][128 * LDT];
    const int t = threadIdx.x;
    const int lane = t & 63;
    const int wave = t >> 6;
    const int wm = wave >> 1, wn = wave & 1;
    const int m0 = blockIdx.x * 128;
    const int n0 = blockIdx.y * 128;
    const int nk = K >> 5;

    const int srow = t >> 1;
    const int sch = (t & 1) * 2;
    const u16* ga = A + (size_t)(m0 + srow) * K + sch * 8;
    const u16* gb = Bt + (size_t)(n0 + srow) * K + sch * 8;
    const int wo = srow * LDT + sch * 8;

    u16x8 ra0 = *(const u16x8*)(ga);
    u16x8 ra1 = *(const u16x8*)(ga + 8);
    u16x8 rb0 = *(const u16x8*)(gb);
    u16x8 rb1 = *(const u16x8*)(gb + 8);
    *(u16x8*)&alds[0][wo] = ra0;  *(u16x8*)&alds[0][wo + 8] = ra1;
    *(u16x8*)&blds[0][wo] = rb0;  *(u16x8*)&blds[0][wo + 8] = rb1;

    f32x4 acc[4][4] = {};
    const int ko = (lane >> 4) * 8;
    const int arow_base = wm * 64 + (lane & 15);
    const int brow_base = wn * 64 + (lane & 15);

    int cur = 0;
    for (int kt = 0; kt < nk; ++kt) {
        __syncthreads();
        if (kt + 1 < nk) {
            const u16* gan = ga + (kt + 1) * 32;
            const u16* gbn = gb + (kt + 1) * 32;
            ra0 = *(const u16x8*)(gan);
            ra1 = *(const u16x8*)(gan + 8);
            rb0 = *(const u16x8*)(gbn);
            rb1 = *(const u16x8*)(gbn + 8);
        }
        bf16x8 afrag[4], bfrag[4];
#pragma unroll
        for (int m = 0; m < 4; ++m)
            afrag[m] = *(const bf16x8*)&alds[cur][(arow_base + m * 16) * LDT + ko];
#pragma unroll
        for (int n = 0; n < 4; ++n)
            bfrag[n] = *(const bf16x8*)&blds[cur][(brow_base + n * 16) * LDT + ko];
#pragma unroll
        for (int m = 0; m < 4; ++m)
#pragma unroll
            for (int n = 0; n < 4; ++n)
                acc[m][n] = __builtin_amdgcn_mfma_f32_16x16x32_bf16(afrag[m], bfrag[n],
                                                                   acc[m][n], 0, 0, 0);
        if (kt + 1 < nk) {
            *(u16x8*)&alds[cur ^ 1][wo] = ra0;  *(u16x8*)&alds[cur ^ 1][wo + 8] = ra1;
            *(u16x8*)&blds[cur ^ 1][wo] = rb0;  *(u16x8*)&blds[cur ^ 1][wo + 8] = rb1;
        }
        cur ^= 1;
    }

#pragma unroll
    for (int m = 0; m < 4; ++m)
#pragma unroll
        for (int n = 0; n < 4; ++n)
#pragma unroll
            for (int r = 0; r < 4; ++r) {
                int row = m0 + wm * 64 + m * 16 + (lane >> 4) * 4 + r;
                int col = n0 + wn * 64 + n * 16 + (lane & 15);
                size_t idx = (size_t)row * N + col;
                if (MODE == 0) Cb[idx] = f2bf(acc[m][n][r]);
                else           X[idx] = acc[m][n][r] + H[idx];
            }
}

// ---------------- V transpose ----------------
__global__ __launch_bounds__(256) void transpose_v_kernel(const u16* __restrict__ qkvb,
                                                          u16* __restrict__ vt) {
    __shared__ u16 tl[64][72];
    const int t = threadIdx.x;
    const int p = blockIdx.y;
    const int nn = p >> 1, b = p & 1;
    const int s0 = blockIdx.x * 64;
    const int r = t >> 2;
    const int ch = (t & 3) * 2;
    const u16* g = qkvb + ((size_t)(s0 + r) * 2 + b) * 3072 + 2048 + nn * 64;
    *(u16x8*)&tl[r][ch * 8]     = *(const u16x8*)(g + ch * 8);
    *(u16x8*)&tl[r][ch * 8 + 8] = *(const u16x8*)(g + ch * 8 + 8);
    __syncthreads();
    const int dh = t >> 2;
    const int sc = (t & 3) * 2;
    u16* o = vt + ((size_t)p * 64 + dh) * 2048 + s0;
#pragma unroll
    for (int q = 0; q < 2; ++q) {
        int scq = sc + q;
        u16x8 v;
#pragma unroll
        for (int j = 0; j < 8; ++j) v[j] = tl[scq * 8 + j][dh];
        *(u16x8*)(o + scq * 8) = v;
    }
}

// ---------------- causal flash attention (swapped QK^T, exp2 units) ----------------
// Q was pre-scaled by 0.125*log2(e) in conv_wt, so scores are in log2 units.
__global__ __launch_bounds__(256) void attn_kernel(const u16* __restrict__ qkvb,
                                                   const u16* __restrict__ vt,
                                                   u16* __restrict__ attnb) {
    constexpr int LKT = 72;               // 64 + 8 pad
    __shared__ u16 klds[64 * LKT];
    __shared__ u16 vlds[64 * LKT];
    __shared__ u16 plds[4][16 * LKT];
    const int t = threadIdx.x;
    const int lane = t & 63;
    const int w = t >> 6;
    const int bid = blockIdx.x;
    const int qt = 31 - (bid >> 5);       // heavy q-tiles dispatched first
    const int p = bid & 31;
    const int nn = p >> 1, b = p & 1;
    const int i0 = qt * 64;

    const int li = lane & 15;             // q-col index (swapped output col)
    const int lg = lane >> 4;             // 16-lane group

    // Q fragments (B-operand rows i = i0 + w*16 + li)
    const int qrow = i0 + w * 16 + li;
    const u16* qg = qkvb + ((size_t)qrow * 2 + b) * 3072 + nn * 64 + lg * 8;
    bf16x8 qa0 = *(const bf16x8*)(qg);
    bf16x8 qa1 = *(const bf16x8*)(qg + 32);

    f32x4 o[4] = {};                      // O[row = lg*4+r][d = cf*16+li]
    float mrun = -3.0e38f;
    float lrun = 0.f;

    const int srow = t >> 2;
    const int sch = (t & 3) * 2;
    const u16* kg = qkvb + 1024 + nn * 64 + sch * 8;
    const u16* vg = vt + ((size_t)p * 64 + srow) * 2048 + sch * 8;

    const int nt = qt + 1;
    u16x8 k0, k1, v0, v1;                 // staged regs for next tile (T14)
    {
        const u16* kgp = kg + ((size_t)srow * 2 + b) * 3072;
        k0 = *(const u16x8*)(kgp);  k1 = *(const u16x8*)(kgp + 8);
        v0 = *(const u16x8*)(vg);   v1 = *(const u16x8*)(vg + 8);
    }
    for (int jt = 0; jt < nt; ++jt) {
        const int j0 = jt * 64;
        __syncthreads();                  // prior tile's LDS reads done
        *(u16x8*)&klds[srow * LKT + sch * 8] = k0;
        *(u16x8*)&klds[srow * LKT + sch * 8 + 8] = k1;
        *(u16x8*)&vlds[srow * LKT + sch * 8] = v0;
        *(u16x8*)&vlds[srow * LKT + sch * 8 + 8] = v1;
        if (jt + 1 < nt) {                // issue-early next-tile loads
            const u16* kgp = kg + ((size_t)(j0 + 64 + srow) * 2 + b) * 3072;
            k0 = *(const u16x8*)(kgp);  k1 = *(const u16x8*)(kgp + 8);
            const u16* vgp = vg + j0 + 64;
            v0 = *(const u16x8*)(vgp);  v1 = *(const u16x8*)(vgp + 8);
        }
        __syncthreads();                  // writes visible

        // swapped QK^T: st[cf][r] = S^T[j = cf*16 + lg*4 + r][i = li]
        f32x4 st[4];
#pragma unroll
        for (int cf = 0; cf < 4; ++cf) {
            bf16x8 kb0 = *(const bf16x8*)&klds[(cf * 16 + li) * LKT + lg * 8];
            bf16x8 kb1 = *(const bf16x8*)&klds[(cf * 16 + li) * LKT + 32 + lg * 8];
            f32x4 z = {};
            z = __builtin_amdgcn_mfma_f32_16x16x32_bf16(kb0, qa0, z, 0, 0, 0);
            z = __builtin_amdgcn_mfma_f32_16x16x32_bf16(kb1, qa1, z, 0, 0, 0);
            st[cf] = z;
        }

        if (jt == qt) {                   // mask only the diagonal tile
            const int it = w * 16 + li;
#pragma unroll
            for (int cf = 0; cf < 4; ++cf)
#pragma unroll
                for (int r = 0; r < 4; ++r) {
                    int jl = cf * 16 + lg * 4 + r;
                    if (jl > it) st[cf][r] = -3.0e38f;
                }
        }

        // row max: 15 in-reg + 2 shuffles (lanes {li, li+16, li+32, li+48} share row)
        float mloc = st[0][0];
#pragma unroll
        for (int cf = 0; cf < 4; ++cf)
#pragma unroll
            for (int r = 0; r < 4; ++r) mloc = fmaxf(mloc, st[cf][r]);
        mloc = fmaxf(mloc, __shfl_xor(mloc, 16, 64));
        mloc = fmaxf(mloc, __shfl_xor(mloc, 32, 64));

        // defer-rescale (T13): only touch o/mrun when max grew past threshold
        if (__any(mloc > mrun + 8.0f)) {
            float mnew = fmaxf(mrun, mloc);
            float alpha = fexp2(mrun - mnew);
            lrun *= alpha;
            mrun = mnew;
#pragma unroll
            for (int r = 0; r < 4; ++r) {
                float ar = __shfl(alpha, lg * 4 + r, 64);
#pragma unroll
                for (int cf = 0; cf < 4; ++cf) o[cf][r] *= ar;
            }
        }

        // P = exp2(s - m), row sum, packed b64 stores (j-contiguous per lane)
        float rsum = 0.f;
#pragma unroll
        for (int cf = 0; cf < 4; ++cf) {
            u16x4 pw;
#pragma unroll
            for (int r = 0; r < 4; ++r) {
                float pv = fexp2(st[cf][r] - mrun);
                rsum += pv;
                pw[r] = f2bf(pv);
            }
            *(u16x4*)&plds[w][li * LKT + cf * 16 + lg * 4] = pw;
        }
        rsum += __shfl_xor(rsum, 16, 64);
        rsum += __shfl_xor(rsum, 32, 64);
        lrun += rsum;

        asm volatile("s_waitcnt lgkmcnt(0)" ::: "memory");
        __builtin_amdgcn_sched_barrier(0);

        // PV: O += P[16][64] x V[64][64]
#pragma unroll
        for (int ks = 0; ks < 2; ++ks) {
            bf16x8 pa = *(const bf16x8*)&plds[w][li * LKT + ks * 32 + lg * 8];
#pragma unroll
            for (int cf = 0; cf < 4; ++cf) {
                bf16x8 vb = *(const bf16x8*)&vlds[(cf * 16 + li) * LKT + ks * 32 + lg * 8];
                o[cf] = __builtin_amdgcn_mfma_f32_16x16x32_bf16(pa, vb, o[cf], 0, 0, 0);
            }
        }
    }

    float rinv = frcp(lrun);
#pragma unroll
    for (int r = 0; r < 4; ++r) {
        float rv = __shfl(rinv, lg * 4 + r, 64);
        int srowg = i0 + w * 16 + lg * 4 + r;
        u16* og = attnb + ((size_t)srowg * 2 + b) * 1024 + nn * 64;
#pragma unroll
        for (int cf = 0; cf < 4; ++cf)
            og[cf * 16 + li] = f2bf(o[cf][r] * rv);
    }
}

// ---------------- residual LayerNorm ----------------
__global__ __launch_bounds__(256) void ln_kernel(const float* __restrict__ X,
                                                 const float* __restrict__ gamma,
                                                 const float* __restrict__ beta,
                                                 float* __restrict__ out) {
    __shared__ float red[8];
    const int t = threadIdx.x;
    const int row = blockIdx.x;
    float4 v = ((const float4*)(X + (size_t)row * 1024))[t];
    float s = v.x + v.y + v.z + v.w;
#pragma unroll
    for (int off = 1; off < 64; off <<= 1) s += __shfl_xor(s, off, 64);
    if ((t & 63) == 0) red[t >> 6] = s;
    __syncthreads();
    float mu = (red[0] + red[1] + red[2] + red[3]) * (1.f / 1024.f);
    float dx = v.x - mu, dy = v.y - mu, dz = v.z - mu, dw = v.w - mu;
    float q = dx * dx + dy * dy + dz * dz + dw * dw;
#pragma unroll
    for (int off = 1; off < 64; off <<= 1) q += __shfl_xor(q, off, 64);
    if ((t & 63) == 0) red[4 + (t >> 6)] = q;
    __syncthreads();
    float var = (red[4] + red[5] + red[6] + red[7]) * (1.f / 1024.f);
    float rs = rsqrtf(var + 1e-5f);
    float4 g = ((const float4*)gamma)[t];
    float4 bt = ((const float4*)beta)[t];
    float4 o;
    o.x = dx * rs * g.x + bt.x;
    o.y = dy * rs * g.y + bt.y;
    o.z = dz * rs * g.z + bt.z;
    o.w = dw * rs * g.w + bt.w;
    ((float4*)(out + (size_t)row * 1024))[t] = o;
}

// ---------------- launch ----------------
extern "C" void kernel_launch(void* const* d_in, const int* in_sizes, int n_in,
                              void* d_out, int out_size, void* d_ws, size_t ws_size,
                              hipStream_t stream) {
    const float* h     = (const float*)d_in[0];
    // d_in[1] = attn_mask (deterministic causal triu; applied analytically)
    const float* Wqkv  = (const float*)d_in[2];
    const float* Wo    = (const float*)d_in[3];
    const float* gamma = (const float*)d_in[4];
    const float* beta  = (const float*)d_in[5];
    float* out = (float*)d_out;

    char* ws = (char*)d_ws;
    u16*   hb    = (u16*)(ws);
    u16*   wqkvt = (u16*)(ws + 8388608);
    u16*   wot   = (u16*)(ws + 14680064);
    u16*   qkvb  = (u16*)(ws + 16777216);
    u16*   vt    = (u16*)(ws + 41943040);
    u16*   attnb = (u16*)(ws + 50331648);
    float* xbuf  = (float*)(ws + 58720256);

    const float qscale = 0.125f * 1.44269504088896f;  // 1/sqrt(Dh) * log2(e)

    conv_h_kernel<<<4096, 256, 0, stream>>>(h, hb);
    conv_wt_kernel<<<dim3(96, 32), 256, 0, stream>>>(Wqkv, wqkvt, 1024, 3072, 1024, qscale);
    conv_wt_kernel<<<dim3(32, 32), 256, 0, stream>>>(Wo, wot, 1024, 1024, 0, 1.0f);
    gemm_bt_kernel<0><<<dim3(32, 24), 256, 0, stream>>>(hb, wqkvt, qkvb, nullptr, nullptr,
                                                        4096, 3072, 1024);
    transpose_v_kernel<<<dim3(32, 32), 256, 0, stream>>>(qkvb, vt);
    attn_kernel<<<1024, 256, 0, stream>>>(qkvb, vt, attnb);
    gemm_bt_kernel<1><<<dim3(32, 8), 256, 0, stream>>>(attnb, wot, nullptr, h, xbuf,
                                                       4096, 1024, 1024);
    ln_kernel<<<4096, 256, 0, stream>>>(xbuf, gamma, beta, out);
}